// Round 14
// baseline (619.178 us; speedup 1.0000x reference)
//
#include <hip/hip_runtime.h>

typedef unsigned int uint_t;
typedef float v4f __attribute__((ext_vector_type(4)));   // native vector for nt loads

#define N_NODES 100000
#define N_EDGES 1600000
#define D 64
#define D2 4096   // D*D
#define D3 12288  // 3*D2

#define NPAD 100352u  // N_NODES rounded up

#define BSHIFT 9          // 512 nodes per bucket
#define BNODES 512
#define NBUCK 196         // ceil(100000/512)
#define CHUNK 8192        // edges per partition block (196 edge blocks)
#define CAP   16384       // fixed stride per bucket (mean fill 8163, ~90 sigma)
#define GRUBLK 3072       // gru blocks in mega1
#define XBLK  ((N_NODES + 255) / 256)   // 391 cast/xform blocks

#define SLICE_US 1600000u               // ushorts per 16-channel slice (N_NODES*16)
#define GCHUNKS  ((N_NODES + 127) / 128)  // 782 node-chunks per gather pass

// ---------- workspace layout (4-byte units) ----------
#define OFF_GI1   0u
#define OFF_GI2   (OFF_GI1 + D3)
#define OFF_GH1   (OFF_GI2 + D3)
#define OFF_GH2   (OFF_GH1 + D3)
#define OFF_W1    (OFF_GH2 + D3)            // 49152  f32[4096] evolved w1
#define OFF_W2    (OFF_W1 + D2)             // 53248  f32[4096] evolved w2
#define OFF_DEG   (OFF_W2 + D2)             // 57344  int[NPAD]
#define OFF_BCUR  (OFF_DEG + NPAD)          // 157696 int[256] (zeroed with deg)
#define OFF_ROWS  (OFF_BCUR + 256u)         // 157952 int[NPAD] rowstart
#define OFF_CSR   (OFF_ROWS + NPAD)         // 258304 int[N_EDGES]
#define OFF_XP    (OFF_CSR + 1600000u)      // 1858304 bf16 x' SLICED [4][N][16] (3.2M units)
#define OFF_Y1    (OFF_XP + 3200000u)       // 5058304 bf16 y1' SLICED [4][N][16] (3.2M units)
#define OFF_PAIRS (OFF_Y1 + 3200000u)       // 8258304 int2[196*CAP] (25.7MB)
#define OFF_G     OFF_PAIRS                 // f32 G[N][64] ALIASES pairs (dead after mega2)
// total ~14.7M units ~= 59 MB

__device__ __forceinline__ float dot4v(v4f a, float4 b, float acc) {
    acc = fmaf(a[0], b.x, acc);
    acc = fmaf(a[1], b.y, acc);
    acc = fmaf(a[2], b.z, acc);
    acc = fmaf(a[3], b.w, acc);
    return acc;
}

// round-to-nearest-even f32 -> bf16
__device__ __forceinline__ uint_t bfr(float f) {
    uint_t u = __float_as_uint(f);
    u += 0x7FFFu + ((u >> 16) & 1u);
    return u >> 16;
}

// pack 64 f32 channels into 4 bf16 slices of [n][16]
__device__ __forceinline__ void store_sliced(
    unsigned short* base, int node, const float* t)
{
#pragma unroll
    for (int p = 0; p < 4; ++p) {
        uint_t pk[8];
#pragma unroll
        for (int j = 0; j < 8; ++j)
            pk[j] = bfr(t[p*16 + 2*j]) | (bfr(t[p*16 + 2*j + 1]) << 16);
        uint4* po = (uint4*)(base + (size_t)p * SLICE_US + (size_t)node * 16);
        po[0] = make_uint4(pk[0], pk[1], pk[2], pk[3]);
        po[1] = make_uint4(pk[4], pk[5], pk[6], pk[7]);
    }
}

// ---- MEGA1: gru matvec (read-ceiling-bound, ~123us measured) OVERLAPPED with
// the fused edge pass (deg count + bucket partition). Edge blocks first.
struct PartLds {
    int hist[256];
    int lbase[256];
    int gbase[256];
    int lcur[256];
    int2 stage[CHUNK];     // 64KB
};
struct GruLds {
    float4 sA[1024];       // 16KB
    float4 sB[1024];       // 16KB
};

__global__ __launch_bounds__(512) void mega1(
    const float* __restrict__ w_ih, const float* __restrict__ w_hh,
    const float* __restrict__ x1, const float* __restrict__ x2,
    const float* __restrict__ h1, const float* __restrict__ h2,
    float* __restrict__ gi1, float* __restrict__ gi2,
    float* __restrict__ gh1, float* __restrict__ gh2,
    const int* __restrict__ src, const int* __restrict__ dst,
    int* __restrict__ deg, int* __restrict__ bcur, int2* __restrict__ pairs)
{
    __shared__ __align__(16) char ldsraw[sizeof(PartLds)];   // 68KB union
    const int tid = threadIdx.x;

    if (blockIdx.x < NBUCK) {
        PartLds& P = *reinterpret_cast<PartLds*>(ldsraw);
        const int e0  = blockIdx.x * CHUNK;
        const int cnt = min(CHUNK, N_EDGES - e0);

        if (tid < 256) { P.hist[tid] = 0; P.lcur[tid] = 0; }
        __syncthreads();
        for (int i = tid; i < cnt; i += 512) {
            const int d = dst[e0 + i];
            atomicAdd(&deg[d], 1);
            atomicAdd(&P.hist[d >> BSHIFT], 1);
        }
        __syncthreads();
        if (tid < 256) P.lbase[tid] = P.hist[tid];
        __syncthreads();
        for (int off = 1; off < 256; off <<= 1) {
            int a = 0, b = 0;
            if (tid < 256) { a = P.lbase[tid]; b = (tid >= off) ? P.lbase[tid - off] : 0; }
            __syncthreads();
            if (tid < 256) P.lbase[tid] = a + b;
            __syncthreads();
        }
        if (tid < 256) {
            const int c = P.hist[tid];
            P.lbase[tid] -= c;
            P.gbase[tid] = c ? atomicAdd(&bcur[tid], c) : 0;
        }
        __syncthreads();
        for (int i = tid; i < cnt; i += 512) {
            const int s = src[e0 + i], d = dst[e0 + i];
            const int b = d >> BSHIFT;
            const int p = P.lbase[b] + atomicAdd(&P.lcur[b], 1);
            P.stage[p] = make_int2(s, d);
        }
        __syncthreads();
        for (int i = tid; i < cnt; i += 512) {
            const int2 v = P.stage[i];
            const int b = v.y >> BSHIFT;
            const int gp = P.gbase[b] + (i - P.lbase[b]);
            if (gp < CAP) pairs[(size_t)b * CAP + gp] = v;
        }
    } else {
        GruLds& G = *reinterpret_cast<GruLds*>(ldsraw);
        const int gb   = blockIdx.x - NBUCK;       // 0..3071
        const int half = (gb >= GRUBLK / 2);
        const int blk  = gb - (half ? GRUBLK / 2 : 0);

        {
            const float4* va = (const float4*)(half ? h1 : x1);
            const float4* vb = (const float4*)(half ? h2 : x2);
#pragma unroll
            for (int i = 0; i < 2; ++i) {
                const int k = tid + i * 512;
                G.sA[k] = va[k];
                G.sB[k] = vb[k];
            }
        }
        __syncthreads();

        const int wave = tid >> 6, lane = tid & 63;
        const int row  = blk * 8 + wave;           // 0..12287
        const v4f* wr = (const v4f*)((half ? w_hh : w_ih) + (size_t)row * D2);

        float p0 = 0.f, p1 = 0.f;
#pragma unroll
        for (int g = 0; g < 4; ++g) {
            v4f a[4];
#pragma unroll
            for (int k = 0; k < 4; ++k)
                a[k] = __builtin_nontemporal_load(&wr[lane + (g * 4 + k) * 64]);
#pragma unroll
            for (int k = 0; k < 4; ++k) {
                const int idx = lane + (g * 4 + k) * 64;
                p0 = dot4v(a[k], G.sA[idx], p0);
                p1 = dot4v(a[k], G.sB[idx], p1);
            }
        }
#pragma unroll
        for (int m = 32; m > 0; m >>= 1) {
            p0 += __shfl_down(p0, m, 64);
            p1 += __shfl_down(p1, m, 64);
        }
        if (lane == 0) {
            float* oA = half ? gh1 : gi1;
            float* oB = half ? gh2 : gi2;
            oA[row] = p0;
            oB[row] = p1;
        }
    }
}

// ---- MEGA2: csr finalize [0,196) || gru gates {196,197} || sliced cast [198,...)
struct CsrLds {
    int lofs[BNODES];
    int lcur[BNODES];
    int pscan[256];
    int bscan[256];
    int stage[CAP];        // 64KB
};

__global__ __launch_bounds__(256) void mega2(
    const int2* __restrict__ pairs, const int* __restrict__ deg,
    const int* __restrict__ bcnt, int* __restrict__ rowstart,
    int* __restrict__ csr_src,
    const float* __restrict__ emb,
    const float* __restrict__ gi1, const float* __restrict__ gh1,
    const float* __restrict__ gi2, const float* __restrict__ gh2,
    const float* __restrict__ b_ih, const float* __restrict__ b_hh,
    const float* __restrict__ hw1, const float* __restrict__ hw2,
    float* __restrict__ w1, float* __restrict__ w2,
    unsigned short* __restrict__ xp)
{
    __shared__ __align__(16) char ldsraw[sizeof(CsrLds)];    // 70KB union
    const int tid = threadIdx.x;

    if (blockIdx.x < NBUCK) {
        CsrLds& L = *reinterpret_cast<CsrLds*>(ldsraw);
        const int b = blockIdx.x;
        const int nodeBase = b << BSHIFT;

        const int cb = (tid < NBUCK) ? bcnt[tid] : 0;
        L.bscan[tid] = cb;
        __syncthreads();
        for (int off = 1; off < 256; off <<= 1) {
            int a = L.bscan[tid];
            int x = (tid >= off) ? L.bscan[tid - off] : 0;
            __syncthreads();
            L.bscan[tid] = a + x;
            __syncthreads();
        }
        const int cnt  = bcnt[b];
        const int base = L.bscan[b] - cnt;

        const int n0 = nodeBase + 2 * tid;
        const int d0 = (n0     < N_NODES) ? deg[n0]     : 0;
        const int d1 = (n0 + 1 < N_NODES) ? deg[n0 + 1] : 0;
        L.pscan[tid] = d0 + d1;
        __syncthreads();
        for (int off = 1; off < 256; off <<= 1) {
            int a = L.pscan[tid];
            int x = (tid >= off) ? L.pscan[tid - off] : 0;
            __syncthreads();
            L.pscan[tid] = a + x;
            __syncthreads();
        }
        const int ex = L.pscan[tid] - (d0 + d1);
        L.lofs[2 * tid]     = ex;
        L.lofs[2 * tid + 1] = ex + d0;
        L.lcur[2 * tid]     = 0;
        L.lcur[2 * tid + 1] = 0;

        if (n0     < N_NODES) rowstart[n0]     = base + ex;
        if (n0 + 1 < N_NODES) rowstart[n0 + 1] = base + ex + d0;
        __syncthreads();

        const int2* bp = pairs + (size_t)b * CAP;
        for (int i = tid; i < cnt; i += 256) {
            const int2 v = bp[i];
            const int ln = v.y - nodeBase;
            const int p  = L.lofs[ln] + atomicAdd(&L.lcur[ln], 1);
            L.stage[p] = v.x;
        }
        __syncthreads();
        for (int i = tid; i < cnt; i += 256)
            csr_src[base + i] = L.stage[i];
    } else if (blockIdx.x < NBUCK + 2) {
        const int layer = blockIdx.x - NBUCK;
        const float* gi = layer ? gi2 : gi1;
        const float* gh = layer ? gh2 : gh1;
        const float* hw = layer ? hw2 : hw1;
        float* wo = layer ? w2 : w1;
#pragma unroll
        for (int i = 0; i < 16; ++i) {
            const int j = tid + i * 256;
            float ir = gi[j]          + b_ih[j];
            float hr = gh[j]          + b_hh[j];
            float iz = gi[j + D2]     + b_ih[j + D2];
            float hz = gh[j + D2]     + b_hh[j + D2];
            float in_ = gi[j + 2*D2]  + b_ih[j + 2*D2];
            float hn = gh[j + 2*D2]   + b_hh[j + 2*D2];
            float r = 1.f / (1.f + expf(-(ir + hr)));
            float z = 1.f / (1.f + expf(-(iz + hz)));
            float n = tanhf(in_ + r * hn);
            wo[j] = (1.f - z) * n + z * hw[j];
        }
    } else {
        // sliced cast x' = bf16(norm * emb), layout [slice][node][16ch]
        const int node = (blockIdx.x - NBUCK - 2) * 256 + tid;
        if (node >= N_NODES) return;
        const float nn = rsqrtf(fmaxf((float)deg[node], 1.0f));
        const float4* p = (const float4*)(emb + (size_t)node * D);
        float t[D];
#pragma unroll
        for (int i = 0; i < 16; ++i) {
            float4 u = p[i];
            t[4*i+0] = u.x * nn; t[4*i+1] = u.y * nn;
            t[4*i+2] = u.z * nn; t[4*i+3] = u.w * nn;
        }
        store_sliced(xp, node, t);
    }
}

// ---- Sliced gather: pass p sums 16-channel slice rows over each node's edges.
// pass = blockIdx.x & 3 so the round-robin block->XCD mapping pins ONE 3.2MB
// slice per XCD's 4MB L2 (R13 diagnosis: 12.8MB working set forced all gathers
// to L3's ~2TB/s random-row ceiling; slice-per-XCD gives 16x reuse at L2 speed).
// 2 lanes per node x 16B; 8-deep independent load batches; no cross-lane ops.
__global__ __launch_bounds__(256) void gather_slice_kernel(
    const unsigned short* __restrict__ xs, const int* __restrict__ csr_src,
    const int* __restrict__ rowstart, const int* __restrict__ degv,
    float* __restrict__ g)
{
    const int tid   = threadIdx.x;
    const int pass  = blockIdx.x & 3;
    const int chunk = blockIdx.x >> 2;
    const int node  = chunk * 128 + (tid >> 1);
    if (node >= N_NODES) return;
    const int half = tid & 1;
    const uint4* sp = (const uint4*)(xs + (size_t)pass * SLICE_US);

    const int beg = rowstart[node];
    const int dg  = degv[node];

    float acc[8];
#pragma unroll
    for (int c = 0; c < 8; ++c) acc[c] = 0.f;

    int k = 0;
    for (; k + 8 <= dg; k += 8) {
        int s[8];
#pragma unroll
        for (int u = 0; u < 8; ++u) s[u] = csr_src[beg + k + u];
        uint4 r[8];
#pragma unroll
        for (int u = 0; u < 8; ++u) r[u] = sp[(size_t)s[u] * 2 + half];
#pragma unroll
        for (int u = 0; u < 8; ++u) {
            acc[0] += __uint_as_float(r[u].x << 16);
            acc[1] += __uint_as_float(r[u].x & 0xFFFF0000u);
            acc[2] += __uint_as_float(r[u].y << 16);
            acc[3] += __uint_as_float(r[u].y & 0xFFFF0000u);
            acc[4] += __uint_as_float(r[u].z << 16);
            acc[5] += __uint_as_float(r[u].z & 0xFFFF0000u);
            acc[6] += __uint_as_float(r[u].w << 16);
            acc[7] += __uint_as_float(r[u].w & 0xFFFF0000u);
        }
    }
    for (; k < dg; ++k) {
        const int s = csr_src[beg + k];
        const uint4 r = sp[(size_t)s * 2 + half];
        acc[0] += __uint_as_float(r.x << 16);
        acc[1] += __uint_as_float(r.x & 0xFFFF0000u);
        acc[2] += __uint_as_float(r.y << 16);
        acc[3] += __uint_as_float(r.y & 0xFFFF0000u);
        acc[4] += __uint_as_float(r.z << 16);
        acc[5] += __uint_as_float(r.z & 0xFFFF0000u);
        acc[6] += __uint_as_float(r.w << 16);
        acc[7] += __uint_as_float(r.w & 0xFFFF0000u);
    }

    float* op = g + (size_t)node * D + pass * 16 + half * 8;
    *(float4*)(op)     = make_float4(acc[0], acc[1], acc[2], acc[3]);
    *(float4*)(op + 4) = make_float4(acc[4], acc[5], acc[6], acc[7]);
}

// ---- Transform: t = G[n]*norm; y = t @ W; layer1 -> bf16 slices of
// norm*relu(y); layer2 -> f32 out.
template <bool LAYER1>
__global__ __launch_bounds__(256) void xform_kernel(
    const float* __restrict__ g, const float* __restrict__ w,
    const int* __restrict__ deg, void* __restrict__ out)
{
    __shared__ float sw[D2];          // 16KB weights
    const int tid = threadIdx.x;
#pragma unroll
    for (int i = 0; i < 16; ++i) sw[tid + i * 256] = w[tid + i * 256];
    __syncthreads();

    const int node = blockIdx.x * 256 + tid;
    if (node >= N_NODES) return;

    const float nn = rsqrtf(fmaxf((float)deg[node], 1.0f));
    float x[D];
    const float4* p = (const float4*)(g + (size_t)node * D);
#pragma unroll
    for (int i = 0; i < 16; ++i) {
        float4 u = p[i];
        x[4*i+0] = u.x * nn; x[4*i+1] = u.y * nn;
        x[4*i+2] = u.z * nn; x[4*i+3] = u.w * nn;
    }

    float acc[D];
#pragma unroll
    for (int j = 0; j < D; ++j) acc[j] = 0.f;
#pragma unroll
    for (int k = 0; k < D; ++k) {
        float a = x[k];
#pragma unroll
        for (int j = 0; j < D; ++j) acc[j] = fmaf(a, sw[k * D + j], acc[j]);
    }

    if (LAYER1) {
        float t[D];
#pragma unroll
        for (int j = 0; j < D; ++j) t[j] = fmaxf(acc[j], 0.f) * nn;
        store_sliced((unsigned short*)out, node, t);
    } else {
        float4* po = (float4*)((float*)out + (size_t)node * D);
#pragma unroll
        for (int i = 0; i < 16; ++i)
            po[i] = make_float4(acc[4*i], acc[4*i+1], acc[4*i+2], acc[4*i+3]);
    }
}

extern "C" void kernel_launch(void* const* d_in, const int* in_sizes, int n_in,
                              void* d_out, int out_size, void* d_ws, size_t ws_size,
                              hipStream_t stream)
{
    const float* emb  = (const float*)d_in[0];
    const float* gc1w = (const float*)d_in[1];
    const float* gc2w = (const float*)d_in[2];
    const float* gc1h = (const float*)d_in[3];
    const float* gc2h = (const float*)d_in[4];
    const float* w_ih = (const float*)d_in[5];
    const float* w_hh = (const float*)d_in[6];
    const float* b_ih = (const float*)d_in[7];
    const float* b_hh = (const float*)d_in[8];
    const int* src = (const int*)d_in[9];
    const int* dst = (const int*)d_in[10];

    float* ws = (float*)d_ws;
    float* gi1 = ws + OFF_GI1;
    float* gi2 = ws + OFF_GI2;
    float* gh1 = ws + OFF_GH1;
    float* gh2 = ws + OFF_GH2;
    float* w1  = ws + OFF_W1;
    float* w2  = ws + OFF_W2;
    int*   deg = (int*)(ws + OFF_DEG);
    int*   bcur = (int*)(ws + OFF_BCUR);
    int*   rows = (int*)(ws + OFF_ROWS);
    int*   csr  = (int*)(ws + OFF_CSR);
    unsigned short* xp = (unsigned short*)(ws + OFF_XP);
    unsigned short* y1 = (unsigned short*)(ws + OFF_Y1);
    int2*  pairs = (int2*)(ws + OFF_PAIRS);
    float* g    = ws + OFF_G;            // aliases pairs (dead after mega2)
    float* out  = (float*)d_out;

    // deg[NPAD] and bcur[256] contiguous: one memset
    hipMemsetAsync(deg, 0, (NPAD + 256) * sizeof(int), stream);

    // gru matvec OVERLAPPED with edge deg+partition
    mega1<<<NBUCK + GRUBLK, 512, 0, stream>>>(
        w_ih, w_hh, gc1h, gc2h, gc1w, gc2w, gi1, gi2, gh1, gh2,
        src, dst, deg, bcur, pairs);

    // CSR finalize || GRU gates -> w1,w2 || sliced cast x'
    mega2<<<NBUCK + 2 + XBLK, 256, 0, stream>>>(
        pairs, deg, bcur, rows, csr, emb,
        gi1, gh1, gi2, gh2, b_ih, b_hh, gc1w, gc2w, w1, w2, xp);

    // layer 1: sliced gather (L2-resident slices) -> transform -> y1' slices
    gather_slice_kernel<<<GCHUNKS * 4, 256, 0, stream>>>(xp, csr, rows, deg, g);
    xform_kernel<true><<<XBLK, 256, 0, stream>>>(g, w1, deg, y1);

    // layer 2: sliced gather -> transform -> f32 out
    gather_slice_kernel<<<GCHUNKS * 4, 256, 0, stream>>>(y1, csr, rows, deg, g);
    xform_kernel<false><<<XBLK, 256, 0, stream>>>(g, w2, deg, out);
}

// Round 15
// 568.066 us; speedup vs baseline: 1.0900x; 1.0900x over previous
//
#include <hip/hip_runtime.h>

typedef unsigned int uint_t;
typedef float v4f __attribute__((ext_vector_type(4)));   // native vector for nt loads

#define N_NODES 100000
#define N_EDGES 1600000
#define D 64
#define D2 4096   // D*D
#define D3 12288  // 3*D2

#define NPAD 100352u  // N_NODES rounded up

#define BSHIFT 9          // 512 nodes per bucket
#define BNODES 512
#define NBUCK 196         // ceil(100000/512)
#define CHUNK 8192        // edges per partition block (196 edge blocks)
#define CAP   16384       // fixed stride per bucket (mean fill 8163, ~90 sigma)
#define GRUBLK 3072       // gru blocks in mega1
#define XBLK  ((N_NODES + 255) / 256)   // 391 cast blocks

// ---------- workspace layout (4-byte units) ----------
#define OFF_GI1   0u
#define OFF_GI2   (OFF_GI1 + D3)
#define OFF_GH1   (OFF_GI2 + D3)
#define OFF_GH2   (OFF_GH1 + D3)
#define OFF_W1    (OFF_GH2 + D3)            // 49152  f32[4096] evolved w1
#define OFF_W2    (OFF_W1 + D2)             // 53248  f32[4096] evolved w2
#define OFF_DEG   (OFF_W2 + D2)             // 57344  int[NPAD]
#define OFF_BCUR  (OFF_DEG + NPAD)          // 157696 int[256] (zeroed with deg)
#define OFF_ROWS  (OFF_BCUR + 256u)         // 157952 int[NPAD] rowstart
#define OFF_CSR   (OFF_ROWS + NPAD)         // 258304 int[N_EDGES]
#define OFF_XP    (OFF_CSR + 1600000u)      // 1858304 bf16 x' = norm*emb (3.2M units)
#define OFF_Y1    (OFF_XP + 3200000u)       // 5058304 bf16 y1' = norm*relu(L1) (3.2M units)
#define OFF_PAIRS (OFF_Y1 + 3200000u)       // 8258304 int2[196*CAP] (25.7MB)
// total ~14.7M units ~= 56 MiB

__device__ __forceinline__ float dot4v(v4f a, float4 b, float acc) {
    acc = fmaf(a[0], b.x, acc);
    acc = fmaf(a[1], b.y, acc);
    acc = fmaf(a[2], b.z, acc);
    acc = fmaf(a[3], b.w, acc);
    return acc;
}

// round-to-nearest-even f32 -> bf16
__device__ __forceinline__ uint_t bfr(float f) {
    uint_t u = __float_as_uint(f);
    u += 0x7FFFu + ((u >> 16) & 1u);
    return u >> 16;
}

// ---- MEGA1: gru matvec (read-ceiling-bound, ~123us measured; 4 structures
// converged at ~3.5 TB/s effective read) OVERLAPPED with the fused edge pass
// (deg count + bucket partition). Edge blocks first so they hide under gru.
struct PartLds {
    int hist[256];
    int lbase[256];
    int gbase[256];
    int lcur[256];
    int2 stage[CHUNK];     // 64KB
};
struct GruLds {
    float4 sA[1024];       // 16KB
    float4 sB[1024];       // 16KB
};

__global__ __launch_bounds__(512) void mega1(
    const float* __restrict__ w_ih, const float* __restrict__ w_hh,
    const float* __restrict__ x1, const float* __restrict__ x2,
    const float* __restrict__ h1, const float* __restrict__ h2,
    float* __restrict__ gi1, float* __restrict__ gi2,
    float* __restrict__ gh1, float* __restrict__ gh2,
    const int* __restrict__ src, const int* __restrict__ dst,
    int* __restrict__ deg, int* __restrict__ bcur, int2* __restrict__ pairs)
{
    __shared__ __align__(16) char ldsraw[sizeof(PartLds)];   // 68KB union
    const int tid = threadIdx.x;

    if (blockIdx.x < NBUCK) {
        PartLds& P = *reinterpret_cast<PartLds*>(ldsraw);
        const int e0  = blockIdx.x * CHUNK;
        const int cnt = min(CHUNK, N_EDGES - e0);

        if (tid < 256) { P.hist[tid] = 0; P.lcur[tid] = 0; }
        __syncthreads();
        for (int i = tid; i < cnt; i += 512) {
            const int d = dst[e0 + i];
            atomicAdd(&deg[d], 1);
            atomicAdd(&P.hist[d >> BSHIFT], 1);
        }
        __syncthreads();
        if (tid < 256) P.lbase[tid] = P.hist[tid];
        __syncthreads();
        for (int off = 1; off < 256; off <<= 1) {
            int a = 0, b = 0;
            if (tid < 256) { a = P.lbase[tid]; b = (tid >= off) ? P.lbase[tid - off] : 0; }
            __syncthreads();
            if (tid < 256) P.lbase[tid] = a + b;
            __syncthreads();
        }
        if (tid < 256) {
            const int c = P.hist[tid];
            P.lbase[tid] -= c;
            P.gbase[tid] = c ? atomicAdd(&bcur[tid], c) : 0;
        }
        __syncthreads();
        for (int i = tid; i < cnt; i += 512) {
            const int s = src[e0 + i], d = dst[e0 + i];
            const int b = d >> BSHIFT;
            const int p = P.lbase[b] + atomicAdd(&P.lcur[b], 1);
            P.stage[p] = make_int2(s, d);
        }
        __syncthreads();
        for (int i = tid; i < cnt; i += 512) {
            const int2 v = P.stage[i];
            const int b = v.y >> BSHIFT;
            const int gp = P.gbase[b] + (i - P.lbase[b]);
            if (gp < CAP) pairs[(size_t)b * CAP + gp] = v;
        }
    } else {
        GruLds& G = *reinterpret_cast<GruLds*>(ldsraw);
        const int gb   = blockIdx.x - NBUCK;       // 0..3071
        const int half = (gb >= GRUBLK / 2);
        const int blk  = gb - (half ? GRUBLK / 2 : 0);

        {
            const float4* va = (const float4*)(half ? h1 : x1);
            const float4* vb = (const float4*)(half ? h2 : x2);
#pragma unroll
            for (int i = 0; i < 2; ++i) {
                const int k = tid + i * 512;
                G.sA[k] = va[k];
                G.sB[k] = vb[k];
            }
        }
        __syncthreads();

        const int wave = tid >> 6, lane = tid & 63;
        const int row  = blk * 8 + wave;           // 0..12287
        const v4f* wr = (const v4f*)((half ? w_hh : w_ih) + (size_t)row * D2);

        float p0 = 0.f, p1 = 0.f;
#pragma unroll
        for (int g = 0; g < 4; ++g) {
            v4f a[4];
#pragma unroll
            for (int k = 0; k < 4; ++k)
                a[k] = __builtin_nontemporal_load(&wr[lane + (g * 4 + k) * 64]);
#pragma unroll
            for (int k = 0; k < 4; ++k) {
                const int idx = lane + (g * 4 + k) * 64;
                p0 = dot4v(a[k], G.sA[idx], p0);
                p1 = dot4v(a[k], G.sB[idx], p1);
            }
        }
#pragma unroll
        for (int m = 32; m > 0; m >>= 1) {
            p0 += __shfl_down(p0, m, 64);
            p1 += __shfl_down(p1, m, 64);
        }
        if (lane == 0) {
            float* oA = half ? gh1 : gi1;
            float* oB = half ? gh2 : gi2;
            oA[row] = p0;
            oB[row] = p1;
        }
    }
}

// ---- MEGA2: three independent jobs, all depending only on mega1:
//   blocks [0,196):   per-bucket CSR finalize
//   blocks 196,197:   GRU gates -> evolved w1/w2 in GLOBAL
//   blocks [198,589): cast x' = bf16(norm[n] * emb[n])  (aggregate-first form)
struct CsrLds {
    int lofs[BNODES];
    int lcur[BNODES];
    int pscan[256];
    int bscan[256];
    int stage[CAP];        // 64KB
};

__global__ __launch_bounds__(256) void mega2(
    const int2* __restrict__ pairs, const int* __restrict__ deg,
    const int* __restrict__ bcnt, int* __restrict__ rowstart,
    int* __restrict__ csr_src,
    const float* __restrict__ emb,
    const float* __restrict__ gi1, const float* __restrict__ gh1,
    const float* __restrict__ gi2, const float* __restrict__ gh2,
    const float* __restrict__ b_ih, const float* __restrict__ b_hh,
    const float* __restrict__ hw1, const float* __restrict__ hw2,
    float* __restrict__ w1, float* __restrict__ w2,
    unsigned short* __restrict__ xp)
{
    __shared__ __align__(16) char ldsraw[sizeof(CsrLds)];    // 70KB union
    const int tid = threadIdx.x;

    if (blockIdx.x < NBUCK) {
        // ---------------- per-bucket CSR finalize ----------------
        CsrLds& L = *reinterpret_cast<CsrLds*>(ldsraw);
        const int b = blockIdx.x;
        const int nodeBase = b << BSHIFT;

        const int cb = (tid < NBUCK) ? bcnt[tid] : 0;
        L.bscan[tid] = cb;
        __syncthreads();
        for (int off = 1; off < 256; off <<= 1) {
            int a = L.bscan[tid];
            int x = (tid >= off) ? L.bscan[tid - off] : 0;
            __syncthreads();
            L.bscan[tid] = a + x;
            __syncthreads();
        }
        const int cnt  = bcnt[b];
        const int base = L.bscan[b] - cnt;

        const int n0 = nodeBase + 2 * tid;
        const int d0 = (n0     < N_NODES) ? deg[n0]     : 0;
        const int d1 = (n0 + 1 < N_NODES) ? deg[n0 + 1] : 0;
        L.pscan[tid] = d0 + d1;
        __syncthreads();
        for (int off = 1; off < 256; off <<= 1) {
            int a = L.pscan[tid];
            int x = (tid >= off) ? L.pscan[tid - off] : 0;
            __syncthreads();
            L.pscan[tid] = a + x;
            __syncthreads();
        }
        const int ex = L.pscan[tid] - (d0 + d1);
        L.lofs[2 * tid]     = ex;
        L.lofs[2 * tid + 1] = ex + d0;
        L.lcur[2 * tid]     = 0;
        L.lcur[2 * tid + 1] = 0;

        if (n0     < N_NODES) rowstart[n0]     = base + ex;
        if (n0 + 1 < N_NODES) rowstart[n0 + 1] = base + ex + d0;
        __syncthreads();

        const int2* bp = pairs + (size_t)b * CAP;
        for (int i = tid; i < cnt; i += 256) {
            const int2 v = bp[i];
            const int ln = v.y - nodeBase;
            const int p  = L.lofs[ln] + atomicAdd(&L.lcur[ln], 1);
            L.stage[p] = v.x;
        }
        __syncthreads();
        for (int i = tid; i < cnt; i += 256)
            csr_src[base + i] = L.stage[i];
    } else if (blockIdx.x < NBUCK + 2) {
        // ---------------- GRU gates -> global w1/w2 ----------------
        const int layer = blockIdx.x - NBUCK;
        const float* gi = layer ? gi2 : gi1;
        const float* gh = layer ? gh2 : gh1;
        const float* hw = layer ? hw2 : hw1;
        float* wo = layer ? w2 : w1;
#pragma unroll
        for (int i = 0; i < 16; ++i) {
            const int j = tid + i * 256;
            float ir = gi[j]          + b_ih[j];
            float hr = gh[j]          + b_hh[j];
            float iz = gi[j + D2]     + b_ih[j + D2];
            float hz = gh[j + D2]     + b_hh[j + D2];
            float in_ = gi[j + 2*D2]  + b_ih[j + 2*D2];
            float hn = gh[j + 2*D2]   + b_hh[j + 2*D2];
            float r = 1.f / (1.f + expf(-(ir + hr)));
            float z = 1.f / (1.f + expf(-(iz + hz)));
            float n = tanhf(in_ + r * hn);
            wo[j] = (1.f - z) * n + z * hw[j];
        }
    } else {
        // ---------------- cast x' = bf16(norm * emb) ----------------
        const int node = (blockIdx.x - NBUCK - 2) * 256 + tid;
        if (node >= N_NODES) return;
        const float nn = rsqrtf(fmaxf((float)deg[node], 1.0f));
        const float4* p = (const float4*)(emb + (size_t)node * D);
        uint_t pk[32];
#pragma unroll
        for (int i = 0; i < 16; ++i) {
            float4 u = p[i];
            pk[2*i]   = bfr(u.x * nn) | (bfr(u.y * nn) << 16);
            pk[2*i+1] = bfr(u.z * nn) | (bfr(u.w * nn) << 16);
        }
        uint4* po = (uint4*)(xp + (size_t)node * D);
#pragma unroll
        for (int i = 0; i < 8; ++i)
            po[i] = make_uint4(pk[4*i], pk[4*i+1], pk[4*i+2], pk[4*i+3]);
    }
}

// ---- Fused GCN layer: (A.x)@W in ONE kernel (aggregate-first identity
// A.(x@W) == (A.x)@W). Gather is VMEM-latency-bound, matvec is LDS/VALU-bound
// -> they overlap across resident blocks instead of running as two serial
// passes. 8 lanes x uint4 per row; LDS handoff with stride-68 padding.
// LAYER1: out = y1' = bf16(norm * relu((A.x)@w1));  else out = f32 final.
template <bool LAYER1>
__global__ __launch_bounds__(256) void gcn_layer_kernel(
    const unsigned short* __restrict__ xbf, const float* __restrict__ w,
    const int* __restrict__ csr_src, const int* __restrict__ rowstart,
    const int* __restrict__ degv, void* __restrict__ out)
{
    __shared__ float sw[D2];          // 16KB weights
    __shared__ float xr[4][8][68];    // 8.7KB per-wave gathered rows (padded)
    const int tid = threadIdx.x;
#pragma unroll
    for (int i = 0; i < 16; ++i) sw[tid + i * 256] = w[tid + i * 256];
    __syncthreads();

    const int node = blockIdx.x * 32 + (tid >> 3);
    const int lg   = tid & 7;          // 16B chunk within the 128B row
    const int wv   = tid >> 6;
    const int slot = (tid >> 3) & 7;
    const uint4* hp = (const uint4*)xbf;
    const bool active = (node < N_NODES);
    int dg = 0;

    if (active) {
        const int beg = rowstart[node];
        dg = degv[node];

        float acc[8];
#pragma unroll
        for (int c = 0; c < 8; ++c) acc[c] = 0.f;

        int k = 0;
        for (; k + 8 <= dg; k += 8) {
            int s[8];
#pragma unroll
            for (int u = 0; u < 8; ++u) s[u] = csr_src[beg + k + u];
            uint4 r[8];
#pragma unroll
            for (int u = 0; u < 8; ++u) r[u] = hp[(size_t)s[u] * 8 + lg];
#pragma unroll
            for (int u = 0; u < 8; ++u) {
                acc[0] += __uint_as_float(r[u].x << 16);
                acc[1] += __uint_as_float(r[u].x & 0xFFFF0000u);
                acc[2] += __uint_as_float(r[u].y << 16);
                acc[3] += __uint_as_float(r[u].y & 0xFFFF0000u);
                acc[4] += __uint_as_float(r[u].z << 16);
                acc[5] += __uint_as_float(r[u].z & 0xFFFF0000u);
                acc[6] += __uint_as_float(r[u].w << 16);
                acc[7] += __uint_as_float(r[u].w & 0xFFFF0000u);
            }
        }
        for (; k < dg; ++k) {
            const int s = csr_src[beg + k];
            const uint4 r = hp[(size_t)s * 8 + lg];
            acc[0] += __uint_as_float(r.x << 16);
            acc[1] += __uint_as_float(r.x & 0xFFFF0000u);
            acc[2] += __uint_as_float(r.y << 16);
            acc[3] += __uint_as_float(r.y & 0xFFFF0000u);
            acc[4] += __uint_as_float(r.z << 16);
            acc[5] += __uint_as_float(r.z & 0xFFFF0000u);
            acc[6] += __uint_as_float(r.w << 16);
            acc[7] += __uint_as_float(r.w & 0xFFFF0000u);
        }

        const float nn = rsqrtf(fmaxf((float)dg, 1.0f));   // dst norm
#pragma unroll
        for (int c = 0; c < 8; ++c) xr[wv][slot][lg * 8 + c] = acc[c] * nn;
    }
    __syncthreads();

    if (active) {
        float o[8];
#pragma unroll
        for (int c = 0; c < 8; ++c) o[c] = 0.f;
#pragma unroll
        for (int k = 0; k < D; ++k) {
            const float xv = xr[wv][slot][k];   // group-broadcast, bank-padded
#pragma unroll
            for (int c = 0; c < 8; ++c)
                o[c] = fmaf(xv, sw[k * D + lg * 8 + c], o[c]);
        }
        if (LAYER1) {
            const float nn = rsqrtf(fmaxf((float)dg, 1.0f));  // next-layer src norm
            float t[8];
#pragma unroll
            for (int c = 0; c < 8; ++c) t[c] = fmaxf(o[c], 0.f) * nn;
            uint4 pk;
            pk.x = bfr(t[0]) | (bfr(t[1]) << 16);
            pk.y = bfr(t[2]) | (bfr(t[3]) << 16);
            pk.z = bfr(t[4]) | (bfr(t[5]) << 16);
            pk.w = bfr(t[6]) | (bfr(t[7]) << 16);
            ((uint4*)out)[(size_t)node * 8 + lg] = pk;
        } else {
            float* op = (float*)out + (size_t)node * D + (size_t)lg * 8;
            *(float4*)(op)     = make_float4(o[0], o[1], o[2], o[3]);
            *(float4*)(op + 4) = make_float4(o[4], o[5], o[6], o[7]);
        }
    }
}

extern "C" void kernel_launch(void* const* d_in, const int* in_sizes, int n_in,
                              void* d_out, int out_size, void* d_ws, size_t ws_size,
                              hipStream_t stream)
{
    const float* emb  = (const float*)d_in[0];
    const float* gc1w = (const float*)d_in[1];
    const float* gc2w = (const float*)d_in[2];
    const float* gc1h = (const float*)d_in[3];
    const float* gc2h = (const float*)d_in[4];
    const float* w_ih = (const float*)d_in[5];
    const float* w_hh = (const float*)d_in[6];
    const float* b_ih = (const float*)d_in[7];
    const float* b_hh = (const float*)d_in[8];
    const int* src = (const int*)d_in[9];
    const int* dst = (const int*)d_in[10];

    float* ws = (float*)d_ws;
    float* gi1 = ws + OFF_GI1;
    float* gi2 = ws + OFF_GI2;
    float* gh1 = ws + OFF_GH1;
    float* gh2 = ws + OFF_GH2;
    float* w1  = ws + OFF_W1;
    float* w2  = ws + OFF_W2;
    int*   deg = (int*)(ws + OFF_DEG);
    int*   bcur = (int*)(ws + OFF_BCUR);
    int*   rows = (int*)(ws + OFF_ROWS);
    int*   csr  = (int*)(ws + OFF_CSR);
    unsigned short* xp = (unsigned short*)(ws + OFF_XP);
    unsigned short* y1 = (unsigned short*)(ws + OFF_Y1);
    int2*  pairs = (int2*)(ws + OFF_PAIRS);
    float* out  = (float*)d_out;

    // deg[NPAD] and bcur[256] contiguous: one memset
    hipMemsetAsync(deg, 0, (NPAD + 256) * sizeof(int), stream);

    // gru matvec OVERLAPPED with edge deg+partition
    mega1<<<NBUCK + GRUBLK, 512, 0, stream>>>(
        w_ih, w_hh, gc1h, gc2h, gc1w, gc2w, gi1, gi2, gh1, gh2,
        src, dst, deg, bcur, pairs);

    // CSR finalize || GRU gates -> w1,w2 || cast x' = bf16(norm*emb)
    mega2<<<NBUCK + 2 + XBLK, 256, 0, stream>>>(
        pairs, deg, bcur, rows, csr, emb,
        gi1, gh1, gi2, gh2, b_ih, b_hh, gc1w, gc2w, w1, w2, xp);

    // layer 1: (A.x')@w1, relu, bf16 store (fused gather+transform)
    gcn_layer_kernel<true><<<(N_NODES + 31) / 32, 256, 0, stream>>>(
        xp, w1, csr, rows, deg, y1);

    // layer 2: (A.y1')@w2 -> f32 out (fused gather+transform)
    gcn_layer_kernel<false><<<(N_NODES + 31) / 32, 256, 0, stream>>>(
        y1, w2, csr, rows, deg, out);
}